// Round 8
// baseline (110.419 us; speedup 1.0000x reference)
//
#include <hip/hip_runtime.h>
#include <hip/hip_bf16.h>
#include <math.h>

#define T_TOK 4096
#define D_MODEL 1024
#define L_LAT 256
#define H_HID 512
#define E_EXP 8
#define SH_HID 512
#define KCAT 768
#define TOT_EROWS (2 * T_TOK)

typedef __bf16 bf16x8 __attribute__((ext_vector_type(8)));
typedef float f32x4 __attribute__((ext_vector_type(4)));

__device__ __forceinline__ unsigned short f2bf(float f) {
    union { float f; unsigned int u; } c{f};
    unsigned int r = (c.u + 0x7fffu + ((c.u >> 16) & 1u)) >> 16;
    return (unsigned short)r;
}
__device__ __forceinline__ unsigned short f2bf_n(float f) {   // native cvt (RNE, cvt_pk-able)
    union { __bf16 h; unsigned short u; } c;
    c.h = (__bf16)f;
    return c.u;
}
__device__ __forceinline__ float bf2f(unsigned short u) {
    union { unsigned int u; float f; } c{(unsigned int)u << 16};
    return c.f;
}

__device__ __forceinline__ void gload_lds16(const unsigned short* g, unsigned short* l) {
    __builtin_amdgcn_global_load_lds(
        (const __attribute__((address_space(1))) void*)g,
        (__attribute__((address_space(3))) void*)l,
        16, 0, 0);
}

// 3-bit XOR slot swizzle for BK=64 rows (8 slots x 8 bf16 = 128 B row). Involution.
__device__ __forceinline__ int swz64(int row, int s) {
    return s ^ (row & 7);
}

// ================= D0: router (exact fp32, w_router in LDS) =================
__global__ __launch_bounds__(256)
void router_kernel(const float* __restrict__ x, const float* __restrict__ w_router,
                   int* __restrict__ topk_idx, float* __restrict__ topk_w)
{
    __shared__ float wlds[E_EXP * D_MODEL];   // 32 KB
    int tid = threadIdx.x;
    for (int i = tid * 4; i < E_EXP * D_MODEL; i += 256 * 4)
        *(float4*)(wlds + i) = *(const float4*)(w_router + i);
    __syncthreads();

    int wid = tid >> 6, lane = tid & 63;
    int t = blockIdx.x * 4 + wid;
    const float* xr = x + (size_t)t * D_MODEL;
    float acc[E_EXP];
#pragma unroll
    for (int e = 0; e < E_EXP; ++e) acc[e] = 0.f;
#pragma unroll 4
    for (int i = 0; i < D_MODEL / 64; ++i) {
        int d = lane + i * 64;
        float xv = xr[d];
#pragma unroll
        for (int e = 0; e < E_EXP; ++e)
            acc[e] = fmaf(xv, wlds[e * D_MODEL + d], acc[e]);
    }
#pragma unroll
    for (int e = 0; e < E_EXP; ++e)
        for (int off = 32; off > 0; off >>= 1)
            acc[e] += __shfl_xor(acc[e], off, 64);
    if (lane == 0) {
        int i0 = 0; float v0 = acc[0];
#pragma unroll
        for (int e = 1; e < E_EXP; ++e) if (acc[e] > v0) { v0 = acc[e]; i0 = e; }
        int i1 = -1; float v1 = -INFINITY;
#pragma unroll
        for (int e = 0; e < E_EXP; ++e) if (e != i0 && acc[e] > v1) { v1 = acc[e]; i1 = e; }
        float e1 = expf(v1 - v0);
        topk_idx[2 * t] = i0; topk_idx[2 * t + 1] = i1;
        topk_w[2 * t] = 1.f / (1.f + e1);
        topk_w[2 * t + 1] = e1 / (1.f + e1);
    }
}

// ================= bucket body (deterministic, no atomics; 256 threads) =========
__device__ void bucket_body(const int* __restrict__ topk_idx,
                            int* __restrict__ counts, int* __restrict__ offsets,
                            int* __restrict__ tok_of_row, int* __restrict__ row_of_pair,
                            int* sb)
{
    int* s_wavecnt  = sb;        // [4][8]
    int* s_wavebase = sb + 32;   // [4][8]
    int* s_tot      = sb + 64;   // [8]
    int* s_off      = sb + 72;   // [8]
    int tid = threadIdx.x, wave = tid >> 6, lane = tid & 63;
    int base_i = tid * 32;       // 8192 items / 256 threads

    int cnt[E_EXP];
#pragma unroll
    for (int e = 0; e < E_EXP; ++e) cnt[e] = 0;
#pragma unroll
    for (int j = 0; j < 32; ++j) {
        int e = topk_idx[base_i + j];
#pragma unroll
        for (int q = 0; q < E_EXP; ++q) cnt[q] += (e == q) ? 1 : 0;
    }
    int excl[E_EXP];
#pragma unroll
    for (int e = 0; e < E_EXP; ++e) {
        int v = cnt[e];
#pragma unroll
        for (int off = 1; off < 64; off <<= 1) {
            int u = __shfl_up(v, off, 64);
            v += (lane >= off) ? u : 0;
        }
        excl[e] = v - cnt[e];
        if (lane == 63) s_wavecnt[wave * 8 + e] = v;
    }
    __syncthreads();
    if (tid < E_EXP) {
        int tot = 0;
        for (int w = 0; w < 4; ++w) tot += s_wavecnt[w * 8 + tid];
        s_tot[tid] = tot;
        counts[tid] = tot;
    }
    __syncthreads();
    if (tid == 0) {
        int off = 0;
        for (int e = 0; e < E_EXP; ++e) { s_off[e] = off; offsets[e] = off; off += s_tot[e]; }
    }
    __syncthreads();
    if (tid < E_EXP) {
        int run = s_off[tid];
        for (int w = 0; w < 4; ++w) { s_wavebase[w * 8 + tid] = run; run += s_wavecnt[w * 8 + tid]; }
    }
    __syncthreads();
    int tb[E_EXP];
#pragma unroll
    for (int e = 0; e < E_EXP; ++e) tb[e] = s_wavebase[wave * 8 + e] + excl[e];
#pragma unroll
    for (int j = 0; j < 32; ++j) {
        int item = base_i + j;
        int e = topk_idx[item];
        int p = 0;
#pragma unroll
        for (int q = 0; q < E_EXP; ++q) if (e == q) { p = tb[q]; tb[q] = p + 1; }
        tok_of_row[p] = item >> 1;
        row_of_pair[item] = p;
    }
}

// ================= fp32-input GEMM tile (reg-staged cvt -> ds_write; uniform) ====
// A: [M][K] f32, B: [N][K] f32. Same LDS layout/swizzle/barriers as bf16 version.
template<bool DUAL, bool SILU>
__device__ void gemm_f32_tile(unsigned short* As, unsigned short* Bs0, unsigned short* Bs1,
                              int m0, int n0,
                              const float* __restrict__ A,
                              const float* __restrict__ B0,
                              const float* __restrict__ B1,
                              unsigned short* __restrict__ C,
                              int K, int ldc)
{
    int tid = threadIdx.x;
    int r8 = tid >> 3, slot = tid & 7;

    const float* aptr[4];
#pragma unroll
    for (int r = 0; r < 4; ++r) {
        int rl = r * 32 + r8;
        aptr[r] = A + (size_t)(m0 + rl) * K + swz64(rl, slot) * 8;
    }
    const float* bptr0[2];
    const float* bptr1[2];
#pragma unroll
    for (int r = 0; r < 2; ++r) {
        int rl = r * 32 + r8;
        int gs = swz64(rl, slot) * 8;
        bptr0[r] = B0 + (size_t)(n0 + rl) * K + gs;
        if (DUAL) bptr1[r] = B1 + (size_t)(n0 + rl) * K + gs;
    }

    int wave = tid >> 6, lane = tid & 63;
    int wm0 = (wave >> 1) * 64, wn0 = (wave & 1) * 32;
    int l15 = lane & 15, kg = lane >> 4;

    f32x4 acc0[4][2] = {};
    f32x4 acc1[DUAL ? 4 : 1][DUAL ? 2 : 1] = {};

    for (int k0 = 0; k0 < K; k0 += 64) {
#pragma unroll
        for (int r = 0; r < 4; ++r) {
            float4 u = *(const float4*)(aptr[r] + k0);
            float4 v = *(const float4*)(aptr[r] + k0 + 4);
            ushort4 lo = { f2bf_n(u.x), f2bf_n(u.y), f2bf_n(u.z), f2bf_n(u.w) };
            ushort4 hi = { f2bf_n(v.x), f2bf_n(v.y), f2bf_n(v.z), f2bf_n(v.w) };
            *(ushort4*)(As + r * 2048 + tid * 8) = lo;
            *(ushort4*)(As + r * 2048 + tid * 8 + 4) = hi;
        }
#pragma unroll
        for (int r = 0; r < 2; ++r) {
            float4 u = *(const float4*)(bptr0[r] + k0);
            float4 v = *(const float4*)(bptr0[r] + k0 + 4);
            ushort4 lo = { f2bf_n(u.x), f2bf_n(u.y), f2bf_n(u.z), f2bf_n(u.w) };
            ushort4 hi = { f2bf_n(v.x), f2bf_n(v.y), f2bf_n(v.z), f2bf_n(v.w) };
            *(ushort4*)(Bs0 + r * 2048 + tid * 8) = lo;
            *(ushort4*)(Bs0 + r * 2048 + tid * 8 + 4) = hi;
            if constexpr (DUAL) {
                float4 p = *(const float4*)(bptr1[r] + k0);
                float4 q = *(const float4*)(bptr1[r] + k0 + 4);
                ushort4 l1 = { f2bf_n(p.x), f2bf_n(p.y), f2bf_n(p.z), f2bf_n(p.w) };
                ushort4 h1 = { f2bf_n(q.x), f2bf_n(q.y), f2bf_n(q.z), f2bf_n(q.w) };
                *(ushort4*)(Bs1 + r * 2048 + tid * 8) = l1;
                *(ushort4*)(Bs1 + r * 2048 + tid * 8 + 4) = h1;
            }
        }
        __syncthreads();

        bf16x8 af[2][4];
#pragma unroll
        for (int kh = 0; kh < 2; ++kh)
#pragma unroll
            for (int mf = 0; mf < 4; ++mf) {
                int row = wm0 + mf * 16 + l15;
                af[kh][mf] = *reinterpret_cast<const bf16x8*>(As + row * 64 + swz64(row, kh * 4 + kg) * 8);
            }
        bf16x8 bf0[2][2], bf1[2][2];
#pragma unroll
        for (int kh = 0; kh < 2; ++kh)
#pragma unroll
            for (int nf = 0; nf < 2; ++nf) {
                int row = wn0 + nf * 16 + l15;
                bf0[kh][nf] = *reinterpret_cast<const bf16x8*>(Bs0 + row * 64 + swz64(row, kh * 4 + kg) * 8);
                if constexpr (DUAL)
                    bf1[kh][nf] = *reinterpret_cast<const bf16x8*>(Bs1 + row * 64 + swz64(row, kh * 4 + kg) * 8);
            }
#pragma unroll
        for (int kh = 0; kh < 2; ++kh)
#pragma unroll
            for (int mf = 0; mf < 4; ++mf)
#pragma unroll
                for (int nf = 0; nf < 2; ++nf) {
                    acc0[mf][nf] = __builtin_amdgcn_mfma_f32_16x16x32_bf16(af[kh][mf], bf0[kh][nf], acc0[mf][nf], 0, 0, 0);
                    if constexpr (DUAL)
                        acc1[mf][nf] = __builtin_amdgcn_mfma_f32_16x16x32_bf16(af[kh][mf], bf1[kh][nf], acc1[mf][nf], 0, 0, 0);
                }
        __syncthreads();
    }

#pragma unroll
    for (int mf = 0; mf < 4; ++mf)
#pragma unroll
        for (int r4 = 0; r4 < 4; ++r4) {
            int mrow = m0 + wm0 + mf * 16 + kg * 4 + r4;
            size_t crow = (size_t)mrow * ldc + n0 + wn0;
#pragma unroll
            for (int nf = 0; nf < 2; ++nf) {
                float v = acc0[mf][nf][r4];
                if constexpr (SILU) {
                    float g = v, a = acc1[mf][nf][r4];
                    v = (g / (1.f + expf(-g))) * a;
                }
                C[crow + nf * 16 + l15] = f2bf(v);
            }
        }
}

// ================= D1 mega: GEMM2 + GEMM1 (fp32-in) + casts + wcat + bucket =====
// bid [0,256): GEMM2 tiles; [256,384): GEMM1; [384,3456): cast wge/w1e/w2e;
// [3456,4224): wcat; ==4224: bucket.
__global__ __launch_bounds__(256)
void mega1_kernel(const float* __restrict__ x,
                  const float* __restrict__ w_down,
                  const float* __restrict__ wg_s, const float* __restrict__ w1_s,
                  const float* __restrict__ wg_e, const float* __restrict__ w1_e,
                  const float* __restrict__ w2_e,
                  const float* __restrict__ w_up, const float* __restrict__ w2_s,
                  unsigned short* __restrict__ lat_bf,
                  unsigned short* __restrict__ acat,
                  unsigned short* __restrict__ wge_bf, unsigned short* __restrict__ w1e_bf,
                  unsigned short* __restrict__ w2e_bf, unsigned short* __restrict__ wcat,
                  const int* __restrict__ topk_idx,
                  int* __restrict__ counts, int* __restrict__ offsets,
                  int* __restrict__ tok_of_row, int* __restrict__ row_of_pair)
{
    __shared__ __align__(16) unsigned short As[128 * 64];   // 16 KB
    __shared__ __align__(16) unsigned short Bs0[64 * 64];   // 8 KB
    __shared__ __align__(16) unsigned short Bs1[64 * 64];   // 8 KB

    int bid = blockIdx.x;
    int tid = threadIdx.x;

    if (bid < 256) {
        int xq = bid & 31, y = bid >> 5;     // y in [0,8)
        gemm_f32_tile<true, true>(As, Bs0, Bs1, xq * 128, y * 64,
            x, wg_s, w1_s, acat + L_LAT, D_MODEL, KCAT);
        return;
    }
    if (bid < 384) {
        int idx = bid - 256;
        int xq = idx & 31, y = idx >> 5;     // y in [0,4)
        gemm_f32_tile<false, false>(As, Bs0, Bs1, xq * 128, y * 64,
            x, w_down, nullptr, lat_bf, D_MODEL, L_LAT);
        return;
    }
    if (bid < 3456) {
        int i = (bid - 384) * 256 + tid;     // [0, 786432)
        const float* src; unsigned short* dst; int base;
        if      (i < 262144) { src = wg_e; dst = wge_bf; base = 0; }
        else if (i < 524288) { src = w1_e; dst = w1e_bf; base = 262144; }
        else                 { src = w2_e; dst = w2e_bf; base = 524288; }
        int j = (i - base) * 4;
        float4 v = *(const float4*)(src + j);
        ushort4 o = { f2bf(v.x), f2bf(v.y), f2bf(v.z), f2bf(v.w) };
        *(ushort4*)(dst + j) = o;
        return;
    }
    if (bid < 4224) {
        int i = (bid - 3456) * 256 + tid;    // [0, 196608)
        int row = i / 192;
        int col = (i % 192) * 4;
        float4 v;
        if (col < 256) v = *(const float4*)(w_up + row * 256 + col);
        else           v = *(const float4*)(w2_s + row * 512 + (col - 256));
        ushort4 o = { f2bf(v.x), f2bf(v.y), f2bf(v.z), f2bf(v.w) };
        *(ushort4*)(wcat + row * KCAT + col) = o;
        return;
    }
    // bid == 4224: bucket
    bucket_body(topk_idx, counts, offsets, tok_of_row, row_of_pair, (int*)As);
}

// ================= D2/D3/D5: proven BK=64 MFMA NT GEMM template =================
template<bool DUAL, bool SILU, bool EXPERT, bool GATHER, bool OUT_BF16>
__global__ __launch_bounds__(256)
void mfma_gemm(const unsigned short* __restrict__ A,
               const unsigned short* __restrict__ B0g,
               const unsigned short* __restrict__ B1g,
               void* __restrict__ Cv,
               int M, int N, int K, int ldc, int ccol,
               const int* __restrict__ tok_of_row,
               const int* __restrict__ offsets,
               const int* __restrict__ counts,
               long strideB)
{
    __shared__ __align__(16) unsigned short As[128 * 64];   // 16 KB
    __shared__ __align__(16) unsigned short Bs0[64 * 64];   // 8 KB
    __shared__ __align__(16) unsigned short Bs1[DUAL ? 64 * 64 : 8];

    int e = EXPERT ? blockIdx.z : 0;
    int m_base = 0, m_count = M;
    if (EXPERT) { m_base = offsets[e]; m_count = counts[e]; }
    int m0 = blockIdx.x * 128;
    if (m0 >= m_count) return;
    int n0 = blockIdx.y * 64;

    const unsigned short* B0 = B0g + (EXPERT ? (size_t)e * strideB : 0);
    const unsigned short* B1 = DUAL ? (B1g + (EXPERT ? (size_t)e * strideB : 0)) : nullptr;

    int tid = threadIdx.x;
    int r8 = tid >> 3, slot = tid & 7;

    const unsigned short* aptr[4];
#pragma unroll
    for (int r = 0; r < 4; ++r) {
        int rl = r * 32 + r8;
        int mrow = m0 + rl;
        if (mrow >= m_count) mrow = m_count - 1;      // clamp (epilogue masks)
        long grow;
        if (GATHER)      grow = tok_of_row[m_base + mrow];
        else if (EXPERT) grow = m_base + mrow;
        else             grow = mrow;
        aptr[r] = A + (size_t)grow * K + swz64(rl, slot) * 8;
    }
    const unsigned short* bptr0[2];
    const unsigned short* bptr1[2];
#pragma unroll
    for (int r = 0; r < 2; ++r) {
        int rl = r * 32 + r8;
        int gs = swz64(rl, slot) * 8;
        bptr0[r] = B0 + (size_t)(n0 + rl) * K + gs;
        if (DUAL) bptr1[r] = B1 + (size_t)(n0 + rl) * K + gs;
    }
    unsigned short* As_dst  = As  + tid * 8;
    unsigned short* Bs0_dst = Bs0 + tid * 8;
    unsigned short* Bs1_dst = DUAL ? (Bs1 + tid * 8) : nullptr;

    int wave = tid >> 6, lane = tid & 63;
    int wm0 = (wave >> 1) * 64, wn0 = (wave & 1) * 32;
    int l15 = lane & 15, kg = lane >> 4;

    f32x4 acc0[4][2] = {};
    f32x4 acc1[DUAL ? 4 : 1][DUAL ? 2 : 1] = {};

    for (int k0 = 0; k0 < K; k0 += 64) {
#pragma unroll
        for (int r = 0; r < 4; ++r)
            gload_lds16(aptr[r] + k0, As_dst + r * 2048);
#pragma unroll
        for (int r = 0; r < 2; ++r) {
            gload_lds16(bptr0[r] + k0, Bs0_dst + r * 2048);
            if constexpr (DUAL) gload_lds16(bptr1[r] + k0, Bs1_dst + r * 2048);
        }
        __syncthreads();

        bf16x8 af[2][4];
#pragma unroll
        for (int kh = 0; kh < 2; ++kh)
#pragma unroll
            for (int mf = 0; mf < 4; ++mf) {
                int row = wm0 + mf * 16 + l15;
                af[kh][mf] = *reinterpret_cast<const bf16x8*>(As + row * 64 + swz64(row, kh * 4 + kg) * 8);
            }
        bf16x8 bf0[2][2], bf1[2][2];
#pragma unroll
        for (int kh = 0; kh < 2; ++kh)
#pragma unroll
            for (int nf = 0; nf < 2; ++nf) {
                int row = wn0 + nf * 16 + l15;
                bf0[kh][nf] = *reinterpret_cast<const bf16x8*>(Bs0 + row * 64 + swz64(row, kh * 4 + kg) * 8);
                if constexpr (DUAL)
                    bf1[kh][nf] = *reinterpret_cast<const bf16x8*>(Bs1 + row * 64 + swz64(row, kh * 4 + kg) * 8);
            }
#pragma unroll
        for (int kh = 0; kh < 2; ++kh)
#pragma unroll
            for (int mf = 0; mf < 4; ++mf)
#pragma unroll
                for (int nf = 0; nf < 2; ++nf) {
                    acc0[mf][nf] = __builtin_amdgcn_mfma_f32_16x16x32_bf16(af[kh][mf], bf0[kh][nf], acc0[mf][nf], 0, 0, 0);
                    if constexpr (DUAL)
                        acc1[mf][nf] = __builtin_amdgcn_mfma_f32_16x16x32_bf16(af[kh][mf], bf1[kh][nf], acc1[mf][nf], 0, 0, 0);
                }
        __syncthreads();
    }

#pragma unroll
    for (int mf = 0; mf < 4; ++mf) {
#pragma unroll
        for (int r4 = 0; r4 < 4; ++r4) {
            int mrow = m0 + wm0 + mf * 16 + kg * 4 + r4;
            if (mrow >= m_count) continue;
            size_t crow = (size_t)((EXPERT ? m_base : 0) + mrow) * ldc + ccol + n0 + wn0;
#pragma unroll
            for (int nf = 0; nf < 2; ++nf) {
                float v = acc0[mf][nf][r4];
                if constexpr (SILU) {
                    float g = v;
                    float a = acc1[mf][nf][r4];
                    v = (g / (1.f + expf(-g))) * a;
                }
                int col = nf * 16 + l15;
                if constexpr (OUT_BF16) ((unsigned short*)Cv)[crow + col] = f2bf(v);
                else                    ((float*)Cv)[crow + col] = v;
            }
        }
    }
}

// ================= D4: combine (bf16 ex) -> acat[:,0:256] =========
__global__ void combine_kernel(const unsigned short* __restrict__ ex,
                               const int* __restrict__ row_of_pair,
                               const float* __restrict__ topk_w,
                               unsigned short* __restrict__ acat)
{
    int i = blockIdx.x * 256 + threadIdx.x;
    int t = i >> 6;
    int l4 = (i & 63) * 4;
    int r0 = row_of_pair[2 * t], r1 = row_of_pair[2 * t + 1];
    float w0 = topk_w[2 * t], w1 = topk_w[2 * t + 1];
    ushort4 a = *(const ushort4*)(ex + (size_t)r0 * L_LAT + l4);
    ushort4 b = *(const ushort4*)(ex + (size_t)r1 * L_LAT + l4);
    ushort4 o = { f2bf(w0 * bf2f(a.x) + w1 * bf2f(b.x)),
                  f2bf(w0 * bf2f(a.y) + w1 * bf2f(b.y)),
                  f2bf(w0 * bf2f(a.z) + w1 * bf2f(b.z)),
                  f2bf(w0 * bf2f(a.w) + w1 * bf2f(b.w)) };
    *(ushort4*)(acat + (size_t)t * KCAT + l4) = o;
}

extern "C" void kernel_launch(void* const* d_in, const int* in_sizes, int n_in,
                              void* d_out, int out_size, void* d_ws, size_t ws_size,
                              hipStream_t stream)
{
    const float* x        = (const float*)d_in[0];
    const float* w_router = (const float*)d_in[1];
    const float* w_down   = (const float*)d_in[2];
    const float* w_up     = (const float*)d_in[3];
    const float* w1_e     = (const float*)d_in[4];
    const float* wg_e     = (const float*)d_in[5];
    const float* w2_e     = (const float*)d_in[6];
    const float* w1_s     = (const float*)d_in[7];
    const float* wg_s     = (const float*)d_in[8];
    const float* w2_s     = (const float*)d_in[9];
    float* out = (float*)d_out;

    char* ws = (char*)d_ws;
    size_t off = 0;
    auto alloc = [&](size_t bytes) -> void* {
        void* p = ws + off;
        off += (bytes + 255) & ~(size_t)255;
        return p;
    };
    unsigned short* hbuf_bf = (unsigned short*)alloc((size_t)TOT_EROWS * H_HID * 2);  // 8 MB
    unsigned short* lat_bf  = (unsigned short*)alloc((size_t)T_TOK * L_LAT * 2);      // 2 MB
    unsigned short* acat    = (unsigned short*)alloc((size_t)T_TOK * KCAT * 2);       // 6 MB
    unsigned short* ex_bf   = (unsigned short*)alloc((size_t)TOT_EROWS * L_LAT * 2);  // 4 MB
    unsigned short* wge_bf  = (unsigned short*)alloc((size_t)E_EXP * H_HID * L_LAT * 2);
    unsigned short* w1e_bf  = (unsigned short*)alloc((size_t)E_EXP * H_HID * L_LAT * 2);
    unsigned short* w2e_bf  = (unsigned short*)alloc((size_t)E_EXP * L_LAT * H_HID * 2);
    unsigned short* wcat_bf = (unsigned short*)alloc((size_t)D_MODEL * KCAT * 2);
    int*   topk_idx    = (int*)alloc(T_TOK * 2 * 4);
    float* topk_w      = (float*)alloc(T_TOK * 2 * 4);
    int*   tok_of_row  = (int*)alloc(T_TOK * 2 * 4);
    int*   row_of_pair = (int*)alloc(T_TOK * 2 * 4);
    int*   counts      = (int*)alloc(E_EXP * 4);
    int*   offsets     = (int*)alloc(E_EXP * 4);

    // D0: router
    router_kernel<<<T_TOK / 4, 256, 0, stream>>>(x, w_router, topk_idx, topk_w);

    // D1: GEMM2 + GEMM1 (fp32-in) + expert-weight casts + wcat + bucket
    mega1_kernel<<<4225, 256, 0, stream>>>(
        x, w_down, wg_s, w1_s, wg_e, w1_e, w2_e, w_up, w2_s,
        lat_bf, acat, wge_bf, w1e_bf, w2e_bf, wcat_bf,
        topk_idx, counts, offsets, tok_of_row, row_of_pair);

    // D2: expert up: hbuf = silu(lat@wg_e^T)*(lat@w1_e^T)  (gathered buckets)
    mfma_gemm<true, true, true, true, true>
        <<<dim3(TOT_EROWS / 128, H_HID / 64, E_EXP), 256, 0, stream>>>(
        lat_bf, wge_bf, w1e_bf, hbuf_bf, 0, H_HID, L_LAT, H_HID, 0,
        tok_of_row, offsets, counts, (long)H_HID * L_LAT);

    // D3: expert down: ex_bf = hbuf @ w2_e^T  (bf16 out)
    mfma_gemm<false, false, true, false, true>
        <<<dim3(TOT_EROWS / 128, L_LAT / 64, E_EXP), 256, 0, stream>>>(
        hbuf_bf, w2e_bf, nullptr, ex_bf, 0, L_LAT, H_HID, L_LAT, 0,
        nullptr, offsets, counts, (long)L_LAT * H_HID);

    // D4: combine -> acat[:,0:256]
    combine_kernel<<<T_TOK * L_LAT / 4 / 256, 256, 0, stream>>>(ex_bf, row_of_pair, topk_w, acat);

    // D5: out = acat @ wcat^T  (fp32 out; 512 blocks = 2/CU)
    mfma_gemm<false, false, false, false, false>
        <<<dim3(T_TOK / 128, D_MODEL / 64, 1), 256, 0, stream>>>(
        acat, wcat_bf, nullptr, out, T_TOK, D_MODEL, KCAT, D_MODEL, 0,
        nullptr, nullptr, nullptr, 0);
}

// Round 9
// 106.426 us; speedup vs baseline: 1.0375x; 1.0375x over previous
//
#include <hip/hip_runtime.h>
#include <hip/hip_bf16.h>
#include <math.h>

#define T_TOK 4096
#define D_MODEL 1024
#define L_LAT 256
#define H_HID 512
#define E_EXP 8
#define SH_HID 512
#define KCAT 768
#define TOT_EROWS (2 * T_TOK)

typedef __bf16 bf16x8 __attribute__((ext_vector_type(8)));
typedef float f32x4 __attribute__((ext_vector_type(4)));

__device__ __forceinline__ unsigned short f2bf(float f) {
    union { float f; unsigned int u; } c{f};
    unsigned int r = (c.u + 0x7fffu + ((c.u >> 16) & 1u)) >> 16;
    return (unsigned short)r;
}
__device__ __forceinline__ float bf2f(unsigned short u) {
    union { unsigned int u; float f; } c{(unsigned int)u << 16};
    return c.f;
}

__device__ __forceinline__ void gload_lds16(const unsigned short* g, unsigned short* l) {
    __builtin_amdgcn_global_load_lds(
        (const __attribute__((address_space(1))) void*)g,
        (__attribute__((address_space(3))) void*)l,
        16, 0, 0);
}

// 3-bit XOR slot swizzle for BK=64 rows (8 slots x 8 bf16 = 128 B row). Involution.
__device__ __forceinline__ int swz64(int row, int s) {
    return s ^ (row & 7);
}

// ================= D1: x-cast + router (jobs) =================
// blocks [0,4096): cast x -> x_bf; [4096,5120): router
__global__ __launch_bounds__(256)
void cast_router_kernel(const float* __restrict__ x, const float* __restrict__ w_router,
                        unsigned short* __restrict__ xb,
                        int* __restrict__ topk_idx, float* __restrict__ topk_w)
{
    __shared__ float wlds[E_EXP * D_MODEL];   // 32 KB (router job only)
    int bid = blockIdx.x;
    int tid = threadIdx.x;

    if (bid < 4096) {
        int i = bid * 256 + tid;       // float4 index over x (1048576 total)
        int j = i * 4;
        float4 v = *(const float4*)(x + j);
        ushort4 o = { f2bf(v.x), f2bf(v.y), f2bf(v.z), f2bf(v.w) };
        *(ushort4*)(xb + j) = o;
        return;
    }

    // ---- router job (exact fp32) ----
    int rb = bid - 4096;
    for (int i = tid * 4; i < E_EXP * D_MODEL; i += 256 * 4)
        *(float4*)(wlds + i) = *(const float4*)(w_router + i);
    __syncthreads();

    int wid = tid >> 6, lane = tid & 63;
    int t = rb * 4 + wid;
    const float* xr = x + (size_t)t * D_MODEL;
    float acc[E_EXP];
#pragma unroll
    for (int e = 0; e < E_EXP; ++e) acc[e] = 0.f;
#pragma unroll 4
    for (int i = 0; i < D_MODEL / 64; ++i) {
        int d = lane + i * 64;
        float xv = xr[d];
#pragma unroll
        for (int e = 0; e < E_EXP; ++e)
            acc[e] = fmaf(xv, wlds[e * D_MODEL + d], acc[e]);
    }
#pragma unroll
    for (int e = 0; e < E_EXP; ++e)
        for (int off = 32; off > 0; off >>= 1)
            acc[e] += __shfl_xor(acc[e], off, 64);
    if (lane == 0) {
        int i0 = 0; float v0 = acc[0];
#pragma unroll
        for (int e = 1; e < E_EXP; ++e) if (acc[e] > v0) { v0 = acc[e]; i0 = e; }
        int i1 = -1; float v1 = -INFINITY;
#pragma unroll
        for (int e = 0; e < E_EXP; ++e) if (e != i0 && acc[e] > v1) { v1 = acc[e]; i1 = e; }
        float e1 = expf(v1 - v0);
        topk_idx[2 * t] = i0; topk_idx[2 * t + 1] = i1;
        topk_w[2 * t] = 1.f / (1.f + e1);
        topk_w[2 * t + 1] = e1 / (1.f + e1);
    }
}

// ================= bucket body (deterministic, no atomics; 256 threads) =========
__device__ void bucket_body(const int* __restrict__ topk_idx,
                            int* __restrict__ counts, int* __restrict__ offsets,
                            int* __restrict__ tok_of_row, int* __restrict__ row_of_pair,
                            int* sb)
{
    int* s_wavecnt  = sb;        // [4][8]
    int* s_wavebase = sb + 32;   // [4][8]
    int* s_tot      = sb + 64;   // [8]
    int* s_off      = sb + 72;   // [8]
    int tid = threadIdx.x, wave = tid >> 6, lane = tid & 63;
    int base_i = tid * 32;       // 8192 items / 256 threads

    int cnt[E_EXP];
#pragma unroll
    for (int e = 0; e < E_EXP; ++e) cnt[e] = 0;
#pragma unroll
    for (int j = 0; j < 32; ++j) {
        int e = topk_idx[base_i + j];
#pragma unroll
        for (int q = 0; q < E_EXP; ++q) cnt[q] += (e == q) ? 1 : 0;
    }
    int excl[E_EXP];
#pragma unroll
    for (int e = 0; e < E_EXP; ++e) {
        int v = cnt[e];
#pragma unroll
        for (int off = 1; off < 64; off <<= 1) {
            int u = __shfl_up(v, off, 64);
            v += (lane >= off) ? u : 0;
        }
        excl[e] = v - cnt[e];
        if (lane == 63) s_wavecnt[wave * 8 + e] = v;
    }
    __syncthreads();
    if (tid < E_EXP) {
        int tot = 0;
        for (int w = 0; w < 4; ++w) tot += s_wavecnt[w * 8 + tid];
        s_tot[tid] = tot;
        counts[tid] = tot;
    }
    __syncthreads();
    if (tid == 0) {
        int off = 0;
        for (int e = 0; e < E_EXP; ++e) { s_off[e] = off; offsets[e] = off; off += s_tot[e]; }
    }
    __syncthreads();
    if (tid < E_EXP) {
        int run = s_off[tid];
        for (int w = 0; w < 4; ++w) { s_wavebase[w * 8 + tid] = run; run += s_wavecnt[w * 8 + tid]; }
    }
    __syncthreads();
    int tb[E_EXP];
#pragma unroll
    for (int e = 0; e < E_EXP; ++e) tb[e] = s_wavebase[wave * 8 + e] + excl[e];
#pragma unroll
    for (int j = 0; j < 32; ++j) {
        int item = base_i + j;
        int e = topk_idx[item];
        int p = 0;
#pragma unroll
        for (int q = 0; q < E_EXP; ++q) if (e == q) { p = tb[q]; tb[q] = p + 1; }
        tok_of_row[p] = item >> 1;
        row_of_pair[item] = p;
    }
}

// ================= D2: GEMM1 + GEMM2 + bucket + weight casts (jobs), BK=64 ======
// bid [0,384): GEMM tiles (x=bid&31, y=bid>>5; y<4 GEMM1, else GEMM2)
// bid == 384: bucket
// bid (384,4225): casts wge/w1e/w2e (3072 blocks) + wcat (768 blocks)
__global__ __launch_bounds__(256)
void k_main(const unsigned short* __restrict__ x_bf,
            const unsigned short* __restrict__ wdown_bf,
            const unsigned short* __restrict__ wgs_bf,
            const unsigned short* __restrict__ w1s_bf,
            const float* __restrict__ wg_e, const float* __restrict__ w1_e,
            const float* __restrict__ w2_e,
            const float* __restrict__ w_up, const float* __restrict__ w2_s,
            unsigned short* __restrict__ lat_bf,
            unsigned short* __restrict__ acat,
            unsigned short* __restrict__ wge_bf, unsigned short* __restrict__ w1e_bf,
            unsigned short* __restrict__ w2e_bf, unsigned short* __restrict__ wcat,
            const int* __restrict__ topk_idx,
            int* __restrict__ counts, int* __restrict__ offsets,
            int* __restrict__ tok_of_row, int* __restrict__ row_of_pair)
{
    __shared__ __align__(16) unsigned short As[128 * 64];   // 16 KB
    __shared__ __align__(16) unsigned short Bs0[64 * 64];   // 8 KB
    __shared__ __align__(16) unsigned short Bs1[64 * 64];   // 8 KB

    int bid = blockIdx.x;
    int tid = threadIdx.x;

    if (bid == 384) {
        bucket_body(topk_idx, counts, offsets, tok_of_row, row_of_pair, (int*)As);
        return;
    }
    if (bid > 384) {
        int i = (bid - 385) * 256 + tid;       // [0, 983040)
        if (i < 786432) {                       // expert-weight casts
            const float* src; unsigned short* dst; int base;
            if      (i < 262144) { src = wg_e; dst = wge_bf; base = 0; }
            else if (i < 524288) { src = w1_e; dst = w1e_bf; base = 262144; }
            else                 { src = w2_e; dst = w2e_bf; base = 524288; }
            int j = (i - base) * 4;
            float4 v = *(const float4*)(src + j);
            ushort4 o = { f2bf(v.x), f2bf(v.y), f2bf(v.z), f2bf(v.w) };
            *(ushort4*)(dst + j) = o;
        } else {                                // wcat build
            int k = i - 786432;                 // [0, 196608)
            int row = k / 192;
            int col = (k % 192) * 4;
            float4 v;
            if (col < 256) v = *(const float4*)(w_up + row * 256 + col);
            else           v = *(const float4*)(w2_s + row * 512 + (col - 256));
            ushort4 o = { f2bf(v.x), f2bf(v.y), f2bf(v.z), f2bf(v.w) };
            *(ushort4*)(wcat + row * KCAT + col) = o;
        }
        return;
    }

    // ---- GEMM jobs (round-6 proven body) ----
    int xq = bid & 31, y = bid >> 5;            // y in [0,12)
    bool dual = (y >= 4);
    int n0 = dual ? (y - 4) * 64 : y * 64;
    const unsigned short* B0 = dual ? wgs_bf : wdown_bf;
    unsigned short* C = dual ? (acat + L_LAT) : lat_bf;   // GEMM2 -> acat cols 256:768
    int ldc = dual ? KCAT : L_LAT;

    int m0 = xq * 128;
    int r8 = tid >> 3, slot = tid & 7;

    const unsigned short* aptr[4];
#pragma unroll
    for (int r = 0; r < 4; ++r) {
        int rl = r * 32 + r8;
        aptr[r] = x_bf + (size_t)(m0 + rl) * D_MODEL + swz64(rl, slot) * 8;
    }
    const unsigned short* bptr0[2];
    const unsigned short* bptr1[2];
#pragma unroll
    for (int r = 0; r < 2; ++r) {
        int rl = r * 32 + r8;
        int gs = swz64(rl, slot) * 8;
        bptr0[r] = B0 + (size_t)(n0 + rl) * D_MODEL + gs;
        bptr1[r] = w1s_bf + (size_t)(n0 + rl) * D_MODEL + gs;
    }
    unsigned short* As_dst  = As  + tid * 8;
    unsigned short* Bs0_dst = Bs0 + tid * 8;
    unsigned short* Bs1_dst = Bs1 + tid * 8;

    int wave = tid >> 6, lane = tid & 63;
    int wm0 = (wave >> 1) * 64, wn0 = (wave & 1) * 32;
    int l15 = lane & 15, kg = lane >> 4;

    f32x4 acc0[4][2] = {};
    f32x4 acc1[4][2] = {};

    for (int k0 = 0; k0 < D_MODEL; k0 += 64) {
#pragma unroll
        for (int r = 0; r < 4; ++r)
            gload_lds16(aptr[r] + k0, As_dst + r * 2048);
#pragma unroll
        for (int r = 0; r < 2; ++r) {
            gload_lds16(bptr0[r] + k0, Bs0_dst + r * 2048);
            if (dual) gload_lds16(bptr1[r] + k0, Bs1_dst + r * 2048);
        }
        __syncthreads();

        bf16x8 af[2][4];
#pragma unroll
        for (int kh = 0; kh < 2; ++kh)
#pragma unroll
            for (int mf = 0; mf < 4; ++mf) {
                int row = wm0 + mf * 16 + l15;
                af[kh][mf] = *reinterpret_cast<const bf16x8*>(As + row * 64 + swz64(row, kh * 4 + kg) * 8);
            }
        bf16x8 bf0[2][2], bf1[2][2];
#pragma unroll
        for (int kh = 0; kh < 2; ++kh)
#pragma unroll
            for (int nf = 0; nf < 2; ++nf) {
                int row = wn0 + nf * 16 + l15;
                bf0[kh][nf] = *reinterpret_cast<const bf16x8*>(Bs0 + row * 64 + swz64(row, kh * 4 + kg) * 8);
            }
        if (dual) {
#pragma unroll
            for (int kh = 0; kh < 2; ++kh)
#pragma unroll
                for (int nf = 0; nf < 2; ++nf) {
                    int row = wn0 + nf * 16 + l15;
                    bf1[kh][nf] = *reinterpret_cast<const bf16x8*>(Bs1 + row * 64 + swz64(row, kh * 4 + kg) * 8);
                }
        }
#pragma unroll
        for (int kh = 0; kh < 2; ++kh)
#pragma unroll
            for (int mf = 0; mf < 4; ++mf)
#pragma unroll
                for (int nf = 0; nf < 2; ++nf)
                    acc0[mf][nf] = __builtin_amdgcn_mfma_f32_16x16x32_bf16(af[kh][mf], bf0[kh][nf], acc0[mf][nf], 0, 0, 0);
        if (dual) {
#pragma unroll
            for (int kh = 0; kh < 2; ++kh)
#pragma unroll
                for (int mf = 0; mf < 4; ++mf)
#pragma unroll
                    for (int nf = 0; nf < 2; ++nf)
                        acc1[mf][nf] = __builtin_amdgcn_mfma_f32_16x16x32_bf16(af[kh][mf], bf1[kh][nf], acc1[mf][nf], 0, 0, 0);
        }
        __syncthreads();
    }

#pragma unroll
    for (int mf = 0; mf < 4; ++mf)
#pragma unroll
        for (int r4 = 0; r4 < 4; ++r4) {
            int mrow = m0 + wm0 + mf * 16 + kg * 4 + r4;
            size_t crow = (size_t)mrow * ldc + n0 + wn0;
#pragma unroll
            for (int nf = 0; nf < 2; ++nf) {
                float v = acc0[mf][nf][r4];
                if (dual) {
                    float g = v, a = acc1[mf][nf][r4];
                    v = (g / (1.f + expf(-g))) * a;
                }
                C[crow + nf * 16 + l15] = f2bf(v);
            }
        }
}

// ================= D3/D4/D6: proven BK=64 MFMA NT GEMM template =================
template<bool DUAL, bool SILU, bool EXPERT, bool GATHER, bool OUT_BF16>
__global__ __launch_bounds__(256)
void mfma_gemm(const unsigned short* __restrict__ A,
               const unsigned short* __restrict__ B0g,
               const unsigned short* __restrict__ B1g,
               void* __restrict__ Cv,
               int M, int N, int K, int ldc, int ccol,
               const int* __restrict__ tok_of_row,
               const int* __restrict__ offsets,
               const int* __restrict__ counts,
               long strideB)
{
    __shared__ __align__(16) unsigned short As[128 * 64];   // 16 KB
    __shared__ __align__(16) unsigned short Bs0[64 * 64];   // 8 KB
    __shared__ __align__(16) unsigned short Bs1[DUAL ? 64 * 64 : 8];

    int e = EXPERT ? blockIdx.z : 0;
    int m_base = 0, m_count = M;
    if (EXPERT) { m_base = offsets[e]; m_count = counts[e]; }
    int m0 = blockIdx.x * 128;
    if (m0 >= m_count) return;
    int n0 = blockIdx.y * 64;

    const unsigned short* B0 = B0g + (EXPERT ? (size_t)e * strideB : 0);
    const unsigned short* B1 = DUAL ? (B1g + (EXPERT ? (size_t)e * strideB : 0)) : nullptr;

    int tid = threadIdx.x;
    int r8 = tid >> 3, slot = tid & 7;

    const unsigned short* aptr[4];
#pragma unroll
    for (int r = 0; r < 4; ++r) {
        int rl = r * 32 + r8;
        int mrow = m0 + rl;
        if (mrow >= m_count) mrow = m_count - 1;      // clamp (epilogue masks)
        long grow;
        if (GATHER)      grow = tok_of_row[m_base + mrow];
        else if (EXPERT) grow = m_base + mrow;
        else             grow = mrow;
        aptr[r] = A + (size_t)grow * K + swz64(rl, slot) * 8;
    }
    const unsigned short* bptr0[2];
    const unsigned short* bptr1[2];
#pragma unroll
    for (int r = 0; r < 2; ++r) {
        int rl = r * 32 + r8;
        int gs = swz64(rl, slot) * 8;
        bptr0[r] = B0 + (size_t)(n0 + rl) * K + gs;
        if (DUAL) bptr1[r] = B1 + (size_t)(n0 + rl) * K + gs;
    }
    unsigned short* As_dst  = As  + tid * 8;
    unsigned short* Bs0_dst = Bs0 + tid * 8;
    unsigned short* Bs1_dst = DUAL ? (Bs1 + tid * 8) : nullptr;

    int wave = tid >> 6, lane = tid & 63;
    int wm0 = (wave >> 1) * 64, wn0 = (wave & 1) * 32;
    int l15 = lane & 15, kg = lane >> 4;

    f32x4 acc0[4][2] = {};
    f32x4 acc1[DUAL ? 4 : 1][DUAL ? 2 : 1] = {};

    for (int k0 = 0; k0 < K; k0 += 64) {
#pragma unroll
        for (int r = 0; r < 4; ++r)
            gload_lds16(aptr[r] + k0, As_dst + r * 2048);
#pragma unroll
        for (int r = 0; r < 2; ++r) {
            gload_lds16(bptr0[r] + k0, Bs0_dst + r * 2048);
            if constexpr (DUAL) gload_lds16(bptr1[r] + k0, Bs1_dst + r * 2048);
        }
        __syncthreads();

        bf16x8 af[2][4];
#pragma unroll
        for (int kh = 0; kh < 2; ++kh)
#pragma unroll
            for (int mf = 0; mf < 4; ++mf) {
                int row = wm0 + mf * 16 + l15;
                af[kh][mf] = *reinterpret_cast<const bf16x8*>(As + row * 64 + swz64(row, kh * 4 + kg) * 8);
            }
        bf16x8 bf0[2][2], bf1[2][2];
#pragma unroll
        for (int kh = 0; kh < 2; ++kh)
#pragma unroll
            for (int nf = 0; nf < 2; ++nf) {
                int row = wn0 + nf * 16 + l15;
                bf0[kh][nf] = *reinterpret_cast<const bf16x8*>(Bs0 + row * 64 + swz64(row, kh * 4 + kg) * 8);
                if constexpr (DUAL)
                    bf1[kh][nf] = *reinterpret_cast<const bf16x8*>(Bs1 + row * 64 + swz64(row, kh * 4 + kg) * 8);
            }
#pragma unroll
        for (int kh = 0; kh < 2; ++kh)
#pragma unroll
            for (int mf = 0; mf < 4; ++mf)
#pragma unroll
                for (int nf = 0; nf < 2; ++nf) {
                    acc0[mf][nf] = __builtin_amdgcn_mfma_f32_16x16x32_bf16(af[kh][mf], bf0[kh][nf], acc0[mf][nf], 0, 0, 0);
                    if constexpr (DUAL)
                        acc1[mf][nf] = __builtin_amdgcn_mfma_f32_16x16x32_bf16(af[kh][mf], bf1[kh][nf], acc1[mf][nf], 0, 0, 0);
                }
        __syncthreads();
    }

#pragma unroll
    for (int mf = 0; mf < 4; ++mf) {
#pragma unroll
        for (int r4 = 0; r4 < 4; ++r4) {
            int mrow = m0 + wm0 + mf * 16 + kg * 4 + r4;
            if (mrow >= m_count) continue;
            size_t crow = (size_t)((EXPERT ? m_base : 0) + mrow) * ldc + ccol + n0 + wn0;
#pragma unroll
            for (int nf = 0; nf < 2; ++nf) {
                float v = acc0[mf][nf][r4];
                if constexpr (SILU) {
                    float g = v;
                    float a = acc1[mf][nf][r4];
                    v = (g / (1.f + expf(-g))) * a;
                }
                int col = nf * 16 + l15;
                if constexpr (OUT_BF16) ((unsigned short*)Cv)[crow + col] = f2bf(v);
                else                    ((float*)Cv)[crow + col] = v;
            }
        }
    }
}

// ================= D5: combine (bf16 ex) -> acat[:,0:256] =========
__global__ void combine_kernel(const unsigned short* __restrict__ ex,
                               const int* __restrict__ row_of_pair,
                               const float* __restrict__ topk_w,
                               unsigned short* __restrict__ acat)
{
    int i = blockIdx.x * 256 + threadIdx.x;
    int t = i >> 6;
    int l4 = (i & 63) * 4;
    int r0 = row_of_pair[2 * t], r1 = row_of_pair[2 * t + 1];
    float w0 = topk_w[2 * t], w1 = topk_w[2 * t + 1];
    ushort4 a = *(const ushort4*)(ex + (size_t)r0 * L_LAT + l4);
    ushort4 b = *(const ushort4*)(ex + (size_t)r1 * L_LAT + l4);
    ushort4 o = { f2bf(w0 * bf2f(a.x) + w1 * bf2f(b.x)),
                  f2bf(w0 * bf2f(a.y) + w1 * bf2f(b.y)),
                  f2bf(w0 * bf2f(a.z) + w1 * bf2f(b.z)),
                  f2bf(w0 * bf2f(a.w) + w1 * bf2f(b.w)) };
    *(ushort4*)(acat + (size_t)t * KCAT + l4) = o;
}

extern "C" void kernel_launch(void* const* d_in, const int* in_sizes, int n_in,
                              void* d_out, int out_size, void* d_ws, size_t ws_size,
                              hipStream_t stream)
{
    const float* x        = (const float*)d_in[0];
    const float* w_router = (const float*)d_in[1];
    const float* w_down   = (const float*)d_in[2];
    const float* w_up     = (const float*)d_in[3];
    const float* w1_e     = (const float*)d_in[4];
    const float* wg_e     = (const float*)d_in[5];
    const float* w2_e     = (const float*)d_in[6];
    const float* w1_s     = (const float*)d_in[7];
    const float* wg_s     = (const float*)d_in[8];
    const float* w2_s     = (const float*)d_in[9];
    float* out = (float*)d_out;

    char* ws = (char*)d_ws;
    size_t off = 0;
    auto alloc = [&](size_t bytes) -> void* {
        void* p = ws + off;
        off += (bytes + 255) & ~(size_t)255;
        return p;
    };
    unsigned short* x_bf    = (unsigned short*)alloc((size_t)T_TOK * D_MODEL * 2);   // 8 MB (also hbuf)
    unsigned short* lat_bf  = (unsigned short*)alloc((size_t)T_TOK * L_LAT * 2);     // 2 MB
    unsigned short* acat    = (unsigned short*)alloc((size_t)T_TOK * KCAT * 2);      // 6 MB
    unsigned short* ex_bf   = (unsigned short*)alloc((size_t)TOT_EROWS * L_LAT * 2); // 4 MB
    unsigned short* wdown_bf= (unsigned short*)alloc((size_t)L_LAT * D_MODEL * 2);
    unsigned short* wge_bf  = (unsigned short*)alloc((size_t)E_EXP * H_HID * L_LAT * 2);
    unsigned short* w1e_bf  = (unsigned short*)alloc((size_t)E_EXP * H_HID * L_LAT * 2);
    unsigned short* w2e_bf  = (unsigned short*)alloc((size_t)E_EXP * L_LAT * H_HID * 2);
    unsigned short* wgs_bf  = (unsigned short*)alloc((size_t)SH_HID * D_MODEL * 2);
    unsigned short* w1s_bf  = (unsigned short*)alloc((size_t)SH_HID * D_MODEL * 2);
    unsigned short* wcat_bf = (unsigned short*)alloc((size_t)D_MODEL * KCAT * 2);
    int*   topk_idx    = (int*)alloc(T_TOK * 2 * 4);
    float* topk_w      = (float*)alloc(T_TOK * 2 * 4);
    int*   tok_of_row  = (int*)alloc(T_TOK * 2 * 4);
    int*   row_of_pair = (int*)alloc(T_TOK * 2 * 4);
    int*   counts      = (int*)alloc(E_EXP * 4);
    int*   offsets     = (int*)alloc(E_EXP * 4);
    unsigned short* hbuf_bf = x_bf;   // alias: x_bf dead after D2

    // D0.5: wdown/wgs/w1s casts are needed by D2's GEMMs -> cast them in D1 too.
    // D1: x-cast + router + {wdown,wgs,w1s} casts
    // blocks: [0,4096) x; [4096,5120) router. wdown/wgs/w1s are small (2.5 MB total):
    // fold into x-cast range by extending the grid.
    // Layout: [0,4096) x-cast; [4096,5120) router; [5120,6400) small-weight casts.
    {
        // reuse cast_router_kernel for x+router; separate tiny kernel unnecessary:
        // extend via a second kernel would add a dispatch — instead fold small weights
        // into k_main? They're needed BY k_main's GEMMs. Must cast in D1.
    }
    // D1a: x-cast + router
    cast_router_kernel<<<5120, 256, 0, stream>>>(x, w_router, x_bf, topk_idx, topk_w);
    // D1b is folded into D1a? No: wdown/wgs/w1s needed by D2 — cast via small grid
    // appended to the SAME kernel is cleaner, but keeping proven code: tiny extra
    // dispatch is avoided by casting them inside cast_router_kernel's x range is not
    // possible without code change; instead cast them in a 1280-block second pass of
    // the same kernel type is overkill. Use combine_kernel-style micro cast below.
    // (327680 float4s for wdown+wgs+w1s = 1280 blocks)
    {
        struct Cast3 { const float* s0; const float* s1; const float* s2; };
    }
    // simple dedicated kernel launch (adds negligible width to D1 window):
    extern __global__ void cast3_kernel(const float*, const float*, const float*,
                                        unsigned short*, unsigned short*, unsigned short*);
    cast3_kernel<<<1280, 256, 0, stream>>>(w_down, wg_s, w1_s, wdown_bf, wgs_bf, w1s_bf);

    // D2: GEMM1 + GEMM2 + bucket + expert-weight/wcat casts
    k_main<<<4225, 256, 0, stream>>>(
        x_bf, wdown_bf, wgs_bf, w1s_bf, wg_e, w1_e, w2_e, w_up, w2_s,
        lat_bf, acat, wge_bf, w1e_bf, w2e_bf, wcat_bf,
        topk_idx, counts, offsets, tok_of_row, row_of_pair);

    // D3: expert up: hbuf = silu(lat@wg_e^T)*(lat@w1_e^T)  (gathered buckets)
    mfma_gemm<true, true, true, true, true>
        <<<dim3(TOT_EROWS / 128, H_HID / 64, E_EXP), 256, 0, stream>>>(
        lat_bf, wge_bf, w1e_bf, hbuf_bf, 0, H_HID, L_LAT, H_HID, 0,
        tok_of_row, offsets, counts, (long)H_HID * L_LAT);

    // D4: expert down: ex_bf = hbuf @ w2_e^T  (bf16 out)
    mfma_gemm<false, false, true, false, true>
        <<<dim3(TOT_EROWS / 128, L_LAT / 64, E_EXP), 256, 0, stream>>>(
        hbuf_bf, w2e_bf, nullptr, ex_bf, 0, L_LAT, H_HID, L_LAT, 0,
        nullptr, offsets, counts, (long)L_LAT * H_HID);

    // D5: combine -> acat[:,0:256]
    combine_kernel<<<T_TOK * L_LAT / 4 / 256, 256, 0, stream>>>(ex_bf, row_of_pair, topk_w, acat);

    // D6: out = acat @ wcat^T  (fp32 out; 512 blocks = 2/CU)
    mfma_gemm<false, false, false, false, false>
        <<<dim3(T_TOK / 128, D_MODEL / 64, 1), 256, 0, stream>>>(
        acat, wcat_bf, nullptr, out, T_TOK, D_MODEL, KCAT, D_MODEL, 0,
        nullptr, nullptr, nullptr, 0);
}

// cast wdown (65536 f4) + wgs (131072 f4) + w1s (131072 f4) = 327680 float4s
__global__ __launch_bounds__(256)
void cast3_kernel(const float* __restrict__ w_down, const float* __restrict__ wg_s,
                  const float* __restrict__ w1_s,
                  unsigned short* __restrict__ wdb, unsigned short* __restrict__ wgsb,
                  unsigned short* __restrict__ w1sb)
{
    int i = blockIdx.x * 256 + threadIdx.x;
    const float* src; unsigned short* dst; int base;
    if      (i < 65536)  { src = w_down; dst = wdb;  base = 0; }
    else if (i < 196608) { src = wg_s;   dst = wgsb; base = 65536; }
    else                 { src = w1_s;   dst = w1sb; base = 196608; }
    int j = (i - base) * 4;
    float4 v = *(const float4*)(src + j);
    ushort4 o = { f2bf(v.x), f2bf(v.y), f2bf(v.z), f2bf(v.w) };
    *(ushort4*)(dst + j) = o;
}

// Round 10
// 91.102 us; speedup vs baseline: 1.2120x; 1.1682x over previous
//
#include <hip/hip_runtime.h>
#include <hip/hip_bf16.h>
#include <math.h>

#define T_TOK 4096
#define D_MODEL 1024
#define L_LAT 256
#define H_HID 512
#define E_EXP 8
#define SH_HID 512
#define TOT_EROWS (2 * T_TOK)

typedef __bf16 bf16x8 __attribute__((ext_vector_type(8)));
typedef float f32x4 __attribute__((ext_vector_type(4)));

__device__ __forceinline__ unsigned short f2bf(float f) {
    union { float f; unsigned int u; } c{f};
    unsigned int r = (c.u + 0x7fffu + ((c.u >> 16) & 1u)) >> 16;
    return (unsigned short)r;
}
__device__ __forceinline__ float bf2f(unsigned short u) {
    union { unsigned int u; float f; } c{(unsigned int)u << 16};
    return c.f;
}

__device__ __forceinline__ void gload_lds16(const unsigned short* g, unsigned short* l) {
    __builtin_amdgcn_global_load_lds(
        (const __attribute__((address_space(1))) void*)g,
        (__attribute__((address_space(3))) void*)l,
        16, 0, 0);
}

// 3-bit XOR slot swizzle for BK=64 rows (8 slots x 8 bf16 = 128 B row). Involution.
__device__ __forceinline__ int swz64(int row, int s) {
    return s ^ (row & 7);
}

// ================= D1: x-cast + router + small-weight casts (jobs) =================
// [0,4096): x cast; [4096,5120): router; [5120,6400): wdown/wgs/w1s casts
__global__ __launch_bounds__(256)
void cast_router_kernel(const float* __restrict__ x, const float* __restrict__ w_router,
                        const float* __restrict__ w_down, const float* __restrict__ wg_s,
                        const float* __restrict__ w1_s,
                        unsigned short* __restrict__ xb, unsigned short* __restrict__ wdb,
                        unsigned short* __restrict__ wgsb, unsigned short* __restrict__ w1sb,
                        int* __restrict__ topk_idx, float* __restrict__ topk_w)
{
    __shared__ float wlds[E_EXP * D_MODEL];   // 32 KB (router job only)
    int bid = blockIdx.x;
    int tid = threadIdx.x;

    if (bid < 4096) {
        int j = (bid * 256 + tid) * 4;
        float4 v = *(const float4*)(x + j);
        ushort4 o = { f2bf(v.x), f2bf(v.y), f2bf(v.z), f2bf(v.w) };
        *(ushort4*)(xb + j) = o;
        return;
    }
    if (bid >= 5120) {
        int i = (bid - 5120) * 256 + tid;      // [0, 327680)
        const float* src; unsigned short* dst; int base;
        if      (i < 65536)  { src = w_down; dst = wdb;  base = 0; }
        else if (i < 196608) { src = wg_s;   dst = wgsb; base = 65536; }
        else                 { src = w1_s;   dst = w1sb; base = 196608; }
        int j = (i - base) * 4;
        float4 v = *(const float4*)(src + j);
        ushort4 o = { f2bf(v.x), f2bf(v.y), f2bf(v.z), f2bf(v.w) };
        *(ushort4*)(dst + j) = o;
        return;
    }

    // ---- router job (exact fp32) ----
    int rb = bid - 4096;
    for (int i = tid * 4; i < E_EXP * D_MODEL; i += 256 * 4)
        *(float4*)(wlds + i) = *(const float4*)(w_router + i);
    __syncthreads();

    int wid = tid >> 6, lane = tid & 63;
    int t = rb * 4 + wid;
    const float* xr = x + (size_t)t * D_MODEL;
    float acc[E_EXP];
#pragma unroll
    for (int e = 0; e < E_EXP; ++e) acc[e] = 0.f;
#pragma unroll 4
    for (int i = 0; i < D_MODEL / 64; ++i) {
        int d = lane + i * 64;
        float xv = xr[d];
#pragma unroll
        for (int e = 0; e < E_EXP; ++e)
            acc[e] = fmaf(xv, wlds[e * D_MODEL + d], acc[e]);
    }
#pragma unroll
    for (int e = 0; e < E_EXP; ++e)
        for (int off = 32; off > 0; off >>= 1)
            acc[e] += __shfl_xor(acc[e], off, 64);
    if (lane == 0) {
        int i0 = 0; float v0 = acc[0];
#pragma unroll
        for (int e = 1; e < E_EXP; ++e) if (acc[e] > v0) { v0 = acc[e]; i0 = e; }
        int i1 = -1; float v1 = -INFINITY;
#pragma unroll
        for (int e = 0; e < E_EXP; ++e) if (e != i0 && acc[e] > v1) { v1 = acc[e]; i1 = e; }
        float e1 = expf(v1 - v0);
        topk_idx[2 * t] = i0; topk_idx[2 * t + 1] = i1;
        topk_w[2 * t] = 1.f / (1.f + e1);
        topk_w[2 * t + 1] = e1 / (1.f + e1);
    }
}

// ================= bucket body (deterministic, no atomics; 256 threads) =========
__device__ void bucket_body(const int* __restrict__ topk_idx,
                            int* __restrict__ counts, int* __restrict__ offsets,
                            int* __restrict__ tok_of_row, int* __restrict__ row_of_pair,
                            int* sb)
{
    int* s_wavecnt  = sb;        // [4][8]
    int* s_wavebase = sb + 32;   // [4][8]
    int* s_tot      = sb + 64;   // [8]
    int* s_off      = sb + 72;   // [8]
    int tid = threadIdx.x, wave = tid >> 6, lane = tid & 63;
    int base_i = tid * 32;       // 8192 items / 256 threads

    int cnt[E_EXP];
#pragma unroll
    for (int e = 0; e < E_EXP; ++e) cnt[e] = 0;
#pragma unroll
    for (int j = 0; j < 32; ++j) {
        int e = topk_idx[base_i + j];
#pragma unroll
        for (int q = 0; q < E_EXP; ++q) cnt[q] += (e == q) ? 1 : 0;
    }
    int excl[E_EXP];
#pragma unroll
    for (int e = 0; e < E_EXP; ++e) {
        int v = cnt[e];
#pragma unroll
        for (int off = 1; off < 64; off <<= 1) {
            int u = __shfl_up(v, off, 64);
            v += (lane >= off) ? u : 0;
        }
        excl[e] = v - cnt[e];
        if (lane == 63) s_wavecnt[wave * 8 + e] = v;
    }
    __syncthreads();
    if (tid < E_EXP) {
        int tot = 0;
        for (int w = 0; w < 4; ++w) tot += s_wavecnt[w * 8 + tid];
        s_tot[tid] = tot;
        counts[tid] = tot;
    }
    __syncthreads();
    if (tid == 0) {
        int off = 0;
        for (int e = 0; e < E_EXP; ++e) { s_off[e] = off; offsets[e] = off; off += s_tot[e]; }
    }
    __syncthreads();
    if (tid < E_EXP) {
        int run = s_off[tid];
        for (int w = 0; w < 4; ++w) { s_wavebase[w * 8 + tid] = run; run += s_wavecnt[w * 8 + tid]; }
    }
    __syncthreads();
    int tb[E_EXP];
#pragma unroll
    for (int e = 0; e < E_EXP; ++e) tb[e] = s_wavebase[wave * 8 + e] + excl[e];
#pragma unroll
    for (int j = 0; j < 32; ++j) {
        int item = base_i + j;
        int e = topk_idx[item];
        int p = 0;
#pragma unroll
        for (int q = 0; q < E_EXP; ++q) if (e == q) { p = tb[q]; tb[q] = p + 1; }
        tok_of_row[p] = item >> 1;
        row_of_pair[item] = p;
    }
}

// ================= proven BK=64 GEMM tile body as device function =================
// OUT_MODE: 0 = f32 store, 1 = bf16 store, 2 = f32 accumulate (+=)
template<bool DUAL, bool SILU, bool EXPERT, bool GATHER, int OUT_MODE>
__device__ void gemm_tile(unsigned short* As, unsigned short* Bs0, unsigned short* Bs1,
                          int m0, int n0, int e,
                          const unsigned short* __restrict__ A,
                          const unsigned short* __restrict__ B0g,
                          const unsigned short* __restrict__ B1g,
                          void* __restrict__ Cv,
                          int M, int K, int ldc,
                          const int* __restrict__ tok_of_row,
                          const int* __restrict__ offsets,
                          const int* __restrict__ counts,
                          long strideB)
{
    int m_base = EXPERT ? offsets[e] : 0;
    int m_count = EXPERT ? counts[e] : M;
    if (m0 >= m_count) return;   // block-uniform

    const unsigned short* B0 = B0g + (EXPERT ? (size_t)e * strideB : 0);
    const unsigned short* B1 = DUAL ? (B1g + (EXPERT ? (size_t)e * strideB : 0)) : nullptr;

    int tid = threadIdx.x;
    int r8 = tid >> 3, slot = tid & 7;

    const unsigned short* aptr[4];
#pragma unroll
    for (int r = 0; r < 4; ++r) {
        int rl = r * 32 + r8;
        int mrow = m0 + rl;
        if (mrow >= m_count) mrow = m_count - 1;      // clamp (epilogue masks)
        long grow;
        if (GATHER)      grow = tok_of_row[m_base + mrow];
        else if (EXPERT) grow = m_base + mrow;
        else             grow = mrow;
        aptr[r] = A + (size_t)grow * K + swz64(rl, slot) * 8;
    }
    const unsigned short* bptr0[2];
    const unsigned short* bptr1[2];
#pragma unroll
    for (int r = 0; r < 2; ++r) {
        int rl = r * 32 + r8;
        int gs = swz64(rl, slot) * 8;
        bptr0[r] = B0 + (size_t)(n0 + rl) * K + gs;
        if (DUAL) bptr1[r] = B1 + (size_t)(n0 + rl) * K + gs;
    }
    unsigned short* As_dst  = As  + tid * 8;
    unsigned short* Bs0_dst = Bs0 + tid * 8;
    unsigned short* Bs1_dst = DUAL ? (Bs1 + tid * 8) : nullptr;

    int wave = tid >> 6, lane = tid & 63;
    int wm0 = (wave >> 1) * 64, wn0 = (wave & 1) * 32;
    int l15 = lane & 15, kg = lane >> 4;

    f32x4 acc0[4][2] = {};
    f32x4 acc1[DUAL ? 4 : 1][DUAL ? 2 : 1] = {};

    for (int k0 = 0; k0 < K; k0 += 64) {
#pragma unroll
        for (int r = 0; r < 4; ++r)
            gload_lds16(aptr[r] + k0, As_dst + r * 2048);
#pragma unroll
        for (int r = 0; r < 2; ++r) {
            gload_lds16(bptr0[r] + k0, Bs0_dst + r * 2048);
            if constexpr (DUAL) gload_lds16(bptr1[r] + k0, Bs1_dst + r * 2048);
        }
        __syncthreads();

        bf16x8 af[2][4];
#pragma unroll
        for (int kh = 0; kh < 2; ++kh)
#pragma unroll
            for (int mf = 0; mf < 4; ++mf) {
                int row = wm0 + mf * 16 + l15;
                af[kh][mf] = *reinterpret_cast<const bf16x8*>(As + row * 64 + swz64(row, kh * 4 + kg) * 8);
            }
        bf16x8 bf0[2][2], bf1[2][2];
#pragma unroll
        for (int kh = 0; kh < 2; ++kh)
#pragma unroll
            for (int nf = 0; nf < 2; ++nf) {
                int row = wn0 + nf * 16 + l15;
                bf0[kh][nf] = *reinterpret_cast<const bf16x8*>(Bs0 + row * 64 + swz64(row, kh * 4 + kg) * 8);
                if constexpr (DUAL)
                    bf1[kh][nf] = *reinterpret_cast<const bf16x8*>(Bs1 + row * 64 + swz64(row, kh * 4 + kg) * 8);
            }
#pragma unroll
        for (int kh = 0; kh < 2; ++kh)
#pragma unroll
            for (int mf = 0; mf < 4; ++mf)
#pragma unroll
                for (int nf = 0; nf < 2; ++nf) {
                    acc0[mf][nf] = __builtin_amdgcn_mfma_f32_16x16x32_bf16(af[kh][mf], bf0[kh][nf], acc0[mf][nf], 0, 0, 0);
                    if constexpr (DUAL)
                        acc1[mf][nf] = __builtin_amdgcn_mfma_f32_16x16x32_bf16(af[kh][mf], bf1[kh][nf], acc1[mf][nf], 0, 0, 0);
                }
        __syncthreads();
    }

#pragma unroll
    for (int mf = 0; mf < 4; ++mf) {
#pragma unroll
        for (int r4 = 0; r4 < 4; ++r4) {
            int mrow = m0 + wm0 + mf * 16 + kg * 4 + r4;
            if (mrow >= m_count) continue;
            size_t crow = (size_t)((EXPERT ? m_base : 0) + mrow) * ldc + n0 + wn0;
#pragma unroll
            for (int nf = 0; nf < 2; ++nf) {
                float v = acc0[mf][nf][r4];
                if constexpr (SILU) {
                    float g = v;
                    float a = acc1[mf][nf][r4];
                    v = (g / (1.f + expf(-g))) * a;
                }
                int col = nf * 16 + l15;
                if constexpr (OUT_MODE == 1)      ((unsigned short*)Cv)[crow + col] = f2bf(v);
                else if constexpr (OUT_MODE == 2) ((float*)Cv)[crow + col] += v;
                else                              ((float*)Cv)[crow + col] = v;
            }
        }
    }
}

// ================= D2: GEMM1 + GEMM2 + bucket + big-weight casts (jobs) ==========
// [0,384): GEMM tiles; ==384: bucket; (384,4225): casts wge/w1e/w2e/w_up/w2_s
__global__ __launch_bounds__(256)
void k_main(const unsigned short* __restrict__ x_bf,
            const unsigned short* __restrict__ wdown_bf,
            const unsigned short* __restrict__ wgs_bf,
            const unsigned short* __restrict__ w1s_bf,
            const float* __restrict__ wg_e, const float* __restrict__ w1_e,
            const float* __restrict__ w2_e,
            const float* __restrict__ w_up, const float* __restrict__ w2_s,
            unsigned short* __restrict__ lat_bf,
            unsigned short* __restrict__ hs,
            unsigned short* __restrict__ wge_bf, unsigned short* __restrict__ w1e_bf,
            unsigned short* __restrict__ w2e_bf, unsigned short* __restrict__ wup_bf,
            unsigned short* __restrict__ w2s_bf,
            const int* __restrict__ topk_idx,
            int* __restrict__ counts, int* __restrict__ offsets,
            int* __restrict__ tok_of_row, int* __restrict__ row_of_pair)
{
    __shared__ __align__(16) unsigned short As[128 * 64];   // 16 KB
    __shared__ __align__(16) unsigned short Bs0[64 * 64];   // 8 KB
    __shared__ __align__(16) unsigned short Bs1[64 * 64];   // 8 KB

    int bid = blockIdx.x;
    int tid = threadIdx.x;

    if (bid == 384) {
        bucket_body(topk_idx, counts, offsets, tok_of_row, row_of_pair, (int*)As);
        return;
    }
    if (bid > 384) {
        int i = (bid - 385) * 256 + tid;       // [0, 983040) float4s
        const float* src; unsigned short* dst; int base;
        if      (i < 262144) { src = wg_e; dst = wge_bf; base = 0; }
        else if (i < 524288) { src = w1_e; dst = w1e_bf; base = 262144; }
        else if (i < 786432) { src = w2_e; dst = w2e_bf; base = 524288; }
        else if (i < 851968) { src = w_up; dst = wup_bf; base = 786432; }
        else                 { src = w2_s; dst = w2s_bf; base = 851968; }
        int j = (i - base) * 4;
        float4 v = *(const float4*)(src + j);
        ushort4 o = { f2bf(v.x), f2bf(v.y), f2bf(v.z), f2bf(v.w) };
        *(ushort4*)(dst + j) = o;
        return;
    }

    // GEMM jobs: y<4 -> GEMM1 (lat, N=256); y>=4 -> GEMM2 (hs, N=512, dual-silu)
    int xq = bid & 31, y = bid >> 5;
    if (y < 4) {
        gemm_tile<false, false, false, false, 1>(As, Bs0, Bs1, xq * 128, y * 64, 0,
            x_bf, wdown_bf, nullptr, lat_bf, T_TOK, D_MODEL, L_LAT,
            nullptr, nullptr, nullptr, 0);
    } else {
        gemm_tile<true, true, false, false, 1>(As, Bs0, Bs1, xq * 128, (y - 4) * 64, 0,
            x_bf, wgs_bf, w1s_bf, hs, T_TOK, D_MODEL, SH_HID,
            nullptr, nullptr, nullptr, 0);
    }
}

// ================= D3: expert-up (bucketed) + shared out-GEMM (jobs) =============
// [0,4096): expert-up tiles (x=t>>6, e=(t>>3)&7, y=t&7), most early-exit
// [4096,4608): out = hs @ w2_s^T  (x=idx&31, y=idx>>5 in [0,16))
__global__ __launch_bounds__(256)
void k_exp_sh(const unsigned short* __restrict__ lat_bf,
              const unsigned short* __restrict__ wge_bf,
              const unsigned short* __restrict__ w1e_bf,
              const unsigned short* __restrict__ hs,
              const unsigned short* __restrict__ w2s_bf,
              unsigned short* __restrict__ hbuf_bf,
              float* __restrict__ out,
              const int* __restrict__ tok_of_row,
              const int* __restrict__ offsets,
              const int* __restrict__ counts)
{
    __shared__ __align__(16) unsigned short As[128 * 64];
    __shared__ __align__(16) unsigned short Bs0[64 * 64];
    __shared__ __align__(16) unsigned short Bs1[64 * 64];

    int bid = blockIdx.x;
    if (bid < 4096) {
        int xq = bid >> 6, e = (bid >> 3) & 7, y = bid & 7;
        gemm_tile<true, true, true, true, 1>(As, Bs0, Bs1, xq * 128, y * 64, e,
            lat_bf, wge_bf, w1e_bf, hbuf_bf, 0, L_LAT, H_HID,
            tok_of_row, offsets, counts, (long)H_HID * L_LAT);
    } else {
        int idx = bid - 4096;
        int xq = idx & 31, y = idx >> 5;     // y in [0,16)
        gemm_tile<false, false, false, false, 0>(As, Bs0, Bs1, xq * 128, y * 64, 0,
            hs, w2s_bf, nullptr, out, T_TOK, SH_HID, D_MODEL,
            nullptr, nullptr, nullptr, 0);
    }
}

// ================= D4: expert-down -> ex_bf =================
__global__ __launch_bounds__(256)
void k_expdown(const unsigned short* __restrict__ hbuf_bf,
               const unsigned short* __restrict__ w2e_bf,
               unsigned short* __restrict__ ex_bf,
               const int* __restrict__ offsets,
               const int* __restrict__ counts)
{
    __shared__ __align__(16) unsigned short As[128 * 64];
    __shared__ __align__(16) unsigned short Bs0[64 * 64];
    __shared__ __align__(16) unsigned short Bs1[8];
    gemm_tile<false, false, true, false, 1>(As, Bs0, Bs1,
        blockIdx.x * 128, blockIdx.y * 64, blockIdx.z,
        hbuf_bf, w2e_bf, nullptr, ex_bf, 0, H_HID, L_LAT,
        nullptr, offsets, counts, (long)L_LAT * H_HID);
}

// ================= D5: combine -> rlat (dense [T][256]) =================
__global__ void combine_kernel(const unsigned short* __restrict__ ex,
                               const int* __restrict__ row_of_pair,
                               const float* __restrict__ topk_w,
                               unsigned short* __restrict__ rlat)
{
    int i = blockIdx.x * 256 + threadIdx.x;
    int t = i >> 6;
    int l4 = (i & 63) * 4;
    int r0 = row_of_pair[2 * t], r1 = row_of_pair[2 * t + 1];
    float w0 = topk_w[2 * t], w1 = topk_w[2 * t + 1];
    ushort4 a = *(const ushort4*)(ex + (size_t)r0 * L_LAT + l4);
    ushort4 b = *(const ushort4*)(ex + (size_t)r1 * L_LAT + l4);
    ushort4 o = { f2bf(w0 * bf2f(a.x) + w1 * bf2f(b.x)),
                  f2bf(w0 * bf2f(a.y) + w1 * bf2f(b.y)),
                  f2bf(w0 * bf2f(a.z) + w1 * bf2f(b.z)),
                  f2bf(w0 * bf2f(a.w) + w1 * bf2f(b.w)) };
    *(ushort4*)(rlat + (size_t)t * L_LAT + l4) = o;
}

// ================= D6: out += rlat @ w_up^T (K=256, fp32 accumulate) =============
__global__ __launch_bounds__(256)
void k_final(const unsigned short* __restrict__ rlat,
             const unsigned short* __restrict__ wup_bf,
             float* __restrict__ out)
{
    __shared__ __align__(16) unsigned short As[128 * 64];
    __shared__ __align__(16) unsigned short Bs0[64 * 64];
    __shared__ __align__(16) unsigned short Bs1[8];
    gemm_tile<false, false, false, false, 2>(As, Bs0, Bs1,
        blockIdx.x * 128, blockIdx.y * 64, 0,
        rlat, wup_bf, nullptr, out, T_TOK, L_LAT, D_MODEL,
        nullptr, nullptr, nullptr, 0);
}

extern "C" void kernel_launch(void* const* d_in, const int* in_sizes, int n_in,
                              void* d_out, int out_size, void* d_ws, size_t ws_size,
                              hipStream_t stream)
{
    const float* x        = (const float*)d_in[0];
    const float* w_router = (const float*)d_in[1];
    const float* w_down   = (const float*)d_in[2];
    const float* w_up     = (const float*)d_in[3];
    const float* w1_e     = (const float*)d_in[4];
    const float* wg_e     = (const float*)d_in[5];
    const float* w2_e     = (const float*)d_in[6];
    const float* w1_s     = (const float*)d_in[7];
    const float* wg_s     = (const float*)d_in[8];
    const float* w2_s     = (const float*)d_in[9];
    float* out = (float*)d_out;

    char* ws = (char*)d_ws;
    size_t off = 0;
    auto alloc = [&](size_t bytes) -> void* {
        void* p = ws + off;
        off += (bytes + 255) & ~(size_t)255;
        return p;
    };
    unsigned short* x_bf    = (unsigned short*)alloc((size_t)T_TOK * D_MODEL * 2);    // 8 MB (alias: hbuf)
    unsigned short* lat_bf  = (unsigned short*)alloc((size_t)T_TOK * L_LAT * 2);      // 2 MB
    unsigned short* hs      = (unsigned short*)alloc((size_t)T_TOK * SH_HID * 2);     // 4 MB
    unsigned short* rlat    = (unsigned short*)alloc((size_t)T_TOK * L_LAT * 2);      // 2 MB
    unsigned short* ex_bf   = (unsigned short*)alloc((size_t)TOT_EROWS * L_LAT * 2);  // 4 MB
    unsigned short* wdown_bf= (unsigned short*)alloc((size_t)L_LAT * D_MODEL * 2);
    unsigned short* wge_bf  = (unsigned short*)alloc((size_t)E_EXP * H_HID * L_LAT * 2);
    unsigned short* w1e_bf  = (unsigned short*)alloc((size_t)E_EXP * H_HID * L_LAT * 2);
    unsigned short* w2e_bf  = (unsigned short*)alloc((size_t)E_EXP * L_LAT * H_HID * 2);
    unsigned short* wgs_bf  = (unsigned short*)alloc((size_t)SH_HID * D_MODEL * 2);
    unsigned short* w1s_bf  = (unsigned short*)alloc((size_t)SH_HID * D_MODEL * 2);
    unsigned short* wup_bf  = (unsigned short*)alloc((size_t)D_MODEL * L_LAT * 2);
    unsigned short* w2s_bf  = (unsigned short*)alloc((size_t)D_MODEL * SH_HID * 2);
    int*   topk_idx    = (int*)alloc(T_TOK * 2 * 4);
    float* topk_w      = (float*)alloc(T_TOK * 2 * 4);
    int*   tok_of_row  = (int*)alloc(T_TOK * 2 * 4);
    int*   row_of_pair = (int*)alloc(T_TOK * 2 * 4);
    int*   counts      = (int*)alloc(E_EXP * 4);
    int*   offsets     = (int*)alloc(E_EXP * 4);
    unsigned short* hbuf_bf = x_bf;   // alias: x_bf dead after D2

    // D1: x-cast + router + small-weight casts
    cast_router_kernel<<<6400, 256, 0, stream>>>(
        x, w_router, w_down, wg_s, w1_s,
        x_bf, wdown_bf, wgs_bf, w1s_bf, topk_idx, topk_w);

    // D2: GEMM1 (lat) + GEMM2 (hs) + bucket + big-weight casts
    k_main<<<4225, 256, 0, stream>>>(
        x_bf, wdown_bf, wgs_bf, w1s_bf, wg_e, w1_e, w2_e, w_up, w2_s,
        lat_bf, hs, wge_bf, w1e_bf, w2e_bf, wup_bf, w2s_bf,
        topk_idx, counts, offsets, tok_of_row, row_of_pair);

    // D3: expert-up (gathered buckets) + shared out-GEMM (out = hs @ w2_s^T)
    k_exp_sh<<<4608, 256, 0, stream>>>(
        lat_bf, wge_bf, w1e_bf, hs, w2s_bf, hbuf_bf, out,
        tok_of_row, offsets, counts);

    // D4: expert-down: ex_bf = hbuf @ w2_e^T
    k_expdown<<<dim3(TOT_EROWS / 128, L_LAT / 64, E_EXP), 256, 0, stream>>>(
        hbuf_bf, w2e_bf, ex_bf, offsets, counts);

    // D5: combine -> rlat
    combine_kernel<<<T_TOK * L_LAT / 4 / 256, 256, 0, stream>>>(
        ex_bf, row_of_pair, topk_w, rlat);

    // D6: out += rlat @ w_up^T
    k_final<<<dim3(T_TOK / 128, D_MODEL / 64), 256, 0, stream>>>(rlat, wup_bf, out);
}